// Round 1
// baseline (421.290 us; speedup 1.0000x reference)
//
#include <hip/hip_runtime.h>
#include <math.h>

// Problem constants
#define T_DIM 16
#define B_DIM 128
#define N_DIM 2048
#define TB    (T_DIM * B_DIM)   // 2048 rows of the GEMM

// Workspace layout (bytes). Total ~36.75 MB.
#define WS_H      0
#define WS_TSUM   33554432
#define WS_PSUM   35651584      // [32][2048] f64 per-rowband col sums
#define WS_PSUM2  36175872      // [32][2048] f64 per-rowband col sq-sums
#define WS_SSUM   36700160
#define WS_SCALE  36716544
#define WS_SHIFT  36732928
#define WS_FLAG   36749312

typedef __attribute__((ext_vector_type(2))) double d2;
typedef __attribute__((ext_vector_type(4))) double d4;

// ---- MFMA f64 wiring probe -------------------------------------------------
__device__ __forceinline__ double probeA(int m, int k) {
    return (double)((m * 7 + k * 13) % 23 - 11);
}
__device__ __forceinline__ double probeB(int k, int n) {
    return (double)((k * 5 + n * 3) % 19 - 9);
}

// Hypothesis encoding fh = ab*4 + dF;  ab = aF + 2*bF.
//  A-form 0: m=l&15,k=l>>4   1: m=l>>2,k=l&3
//  B-form 0: n=l&15,k=l>>4   1: n=l>>2,k=l&3
//  D-form 0: i=4*(l>>4)+r,j=l&15   1: i=(l>>4)+4r,j=l&15
//         2: j=4*(l>>4)+r,i=l&15   3: j=(l>>4)+4r,i=l&15
__global__ void mfma_probe_kernel(unsigned int* flag) {
    int l = threadIdx.x;                 // one wave
    __shared__ double Cref[16][16];
    int i0 = l >> 2, j0 = (l & 3) << 2;
    for (int jj = 0; jj < 4; ++jj) {
        double s = 0.0;
        for (int k = 0; k < 4; ++k) s += probeA(i0, k) * probeB(k, j0 + jj);
        Cref[i0][j0 + jj] = s;
    }
    __syncthreads();
    unsigned int win = 0xFFFFFFFFu;
    for (int ab = 0; ab < 4; ++ab) {
        int aF = ab & 1, bF = (ab >> 1) & 1;
        int mA = aF ? (l >> 2) : (l & 15);
        int kA = aF ? (l & 3)  : (l >> 4);
        int nB = bF ? (l >> 2) : (l & 15);
        int kB = bF ? (l & 3)  : (l >> 4);
        d4 d = (d4)0.0;
        d = __builtin_amdgcn_mfma_f64_16x16x4f64(probeA(mA, kA), probeB(kB, nB), d, 0, 0, 0);
        for (int dF = 0; dF < 4; ++dF) {
            double err = 0.0;
            for (int r = 0; r < 4; ++r) {
                int ii, jj;
                if (dF == 0)      { ii = 4 * (l >> 4) + r; jj = l & 15; }
                else if (dF == 1) { ii = (l >> 4) + 4 * r; jj = l & 15; }
                else if (dF == 2) { jj = 4 * (l >> 4) + r; ii = l & 15; }
                else              { jj = (l >> 4) + 4 * r; ii = l & 15; }
                err = fmax(err, fabs(d[r] - Cref[ii][jj]));
            }
            for (int off = 1; off < 64; off <<= 1)
                err = fmax(err, __shfl_xor(err, off, 64));
            if (err < 1e-9 && win == 0xFFFFFFFFu)
                win = (unsigned)(ab * 4 + dF);
        }
    }
    if (l == 0) flag[0] = win;
}

// ---- spatial sum over last dim: one block per (t,b) row -------------------
__global__ __launch_bounds__(256)
void spatial_sum_kernel(const float* __restrict__ x, double* __restrict__ ssum) {
    int row = blockIdx.x;
    int tid = threadIdx.x;
    const float* xr = x + (size_t)row * N_DIM;
    double s = 0.0;
    for (int i = tid; i < N_DIM; i += 256) s += (double)xr[i];
    for (int off = 32; off > 0; off >>= 1) s += __shfl_down(s, off, 64);
    __shared__ double wsum[4];
    int lane = tid & 63, wv = tid >> 6;
    if (lane == 0) wsum[wv] = s;
    __syncthreads();
    if (tid == 0) ssum[row] = (wsum[0] + wsum[1]) + (wsum[2] + wsum[3]);
}

// ---- temporal sum over t: one thread per (b,n) ----------------------------
__global__ __launch_bounds__(256)
void temporal_sum_kernel(const float* __restrict__ x, double* __restrict__ tsum) {
    int idx = blockIdx.x * 256 + threadIdx.x;
    double s = 0.0;
    for (int t = 0; t < T_DIM; ++t)
        s += (double)x[(size_t)t * (B_DIM * N_DIM) + idx];
    tsum[idx] = s;
}

// ---- GEMM h[row,m] = sum_n x[row,n] * W[m,n] ------------------------------
// v11: DUAL-PIPE HYBRID. MI355X has equal FP64 matrix and FP64 vector rates
// (78.6 TF each). v10 ran all blocks on the matrix pipe (MfmaUtil 80%,
// VALUBusy 9%). Now blocks split 50/50 between the MFMA path and a pure
// f64-VALU path by parity of (bid>>8): co-resident blocks on one CU are
// bid-strided by 256 (1024 blocks round-robin over 8 XCDs x 32 CUs), so
// this parity guarantees each CU hosts BOTH pipe types simultaneously.
// Vector path upgraded: f32->f64 convert moved to staging time (LDS holds
// f64, stride 68 doubles = 34.8KB/block), inner loop is pure
// 8x ds_read_b128 + 64x v_fma_f64 per k (no cvt on the DP pipe).
#define BK 16
#define SDD 68    // f64 vector path stride (doubles)
#define STRD 80   // mfma path stride (2-way aliasing = free)

#define MFMA_LOAD(koff)                                             \
    _Pragma("unroll")                                               \
    for (int j = 0; j < 4; ++j) {                                   \
        sa[j] = *(const float4*)(Ag + (koff) + 4 * j);              \
        sb[j] = *(const float4*)(Bg + (koff) + 4 * j);              \
    }

#define MFMA_STAGE(Ab, Bb)                                          \
    _Pragma("unroll")                                               \
    for (int j = 0; j < 4; ++j) {                                   \
        (Ab)[(4 * j + 0) * STRD + lane] = sa[j].x;                  \
        (Ab)[(4 * j + 1) * STRD + lane] = sa[j].y;                  \
        (Ab)[(4 * j + 2) * STRD + lane] = sa[j].z;                  \
        (Ab)[(4 * j + 3) * STRD + lane] = sa[j].w;                  \
        (Bb)[(4 * j + 0) * STRD + lane] = sb[j].x;                  \
        (Bb)[(4 * j + 1) * STRD + lane] = sb[j].y;                  \
        (Bb)[(4 * j + 2) * STRD + lane] = sb[j].z;                  \
        (Bb)[(4 * j + 3) * STRD + lane] = sb[j].w;                  \
    }

#define MFMA_COMPUTE(Ab, Bb)                                        \
    _Pragma("unroll")                                               \
    for (int jq = 0; jq < 4; ++jq) {                                \
        double av[4], bv[4];                                        \
        _Pragma("unroll")                                           \
        for (int f = 0; f < 4; ++f)                                 \
            av[f] = (double)(Ab)[(4 * jq + kA) * STRD + 16 * f + mA]; \
        _Pragma("unroll")                                           \
        for (int g = 0; g < 4; ++g)                                 \
            bv[g] = (double)(Bb)[(4 * jq + kB) * STRD + 16 * g + nB]; \
        _Pragma("unroll")                                           \
        for (int f = 0; f < 4; ++f)                                 \
            _Pragma("unroll")                                       \
            for (int g = 0; g < 4; ++g)                             \
                acc[f][g] = __builtin_amdgcn_mfma_f64_16x16x4f64(   \
                    av[f], bv[g], acc[f][g], 0, 0, 0);              \
    }

__global__ __launch_bounds__(128, 2)
void gemm_hybrid(const float* __restrict__ A, const float* __restrict__ Bw,
                 double* __restrict__ C, double* __restrict__ psum,
                 double* __restrict__ psum2, const unsigned int* __restrict__ flag) {
    __shared__ __align__(16) char smem[40960];   // mfma: 2w x 2buf x 10240B; vec: 34816B; cbuf 32KB
    const int t    = threadIdx.x;
    const int lane = t & 63;
    const int w    = t >> 6;
    const int row0 = blockIdx.y * 64;
    const int col0 = blockIdx.x * 64;
    const int band = blockIdx.y;
    const unsigned int fh = flag[0];

    const float* Ag = A  + (size_t)(row0 + lane) * N_DIM;
    const float* Bg = Bw + (size_t)(col0 + lane) * N_DIM;
    const int kw = w * BK;
    double* cbuf = (double*)smem;                // 4096 doubles = 32KB

    // Dual-pipe split: co-resident blocks are bid-strided by 256; parity of
    // bid>>8 == parity of blockIdx.y>>3 mixes both paths on every CU.
    const bool use_mfma = (fh <= 15u) && (((blockIdx.y >> 3) & 1) == 0);

    if (use_mfma) {
        // ================= MFMA (matrix-pipe) path =================
        const int dF = fh & 3, ab = fh >> 2;
        const int aF = ab & 1, bF = (ab >> 1) & 1;
        const int mA = aF ? (lane >> 2) : (lane & 15);
        const int kA = aF ? (lane & 3)  : (lane >> 4);
        const int nB = bF ? (lane >> 2) : (lane & 15);
        const int kB = bF ? (lane & 3)  : (lane >> 4);
        int iD[4], jD[4];
#pragma unroll
        for (int r = 0; r < 4; ++r) {
            if (dF == 0)      { iD[r] = 4 * (lane >> 4) + r; jD[r] = lane & 15; }
            else if (dF == 1) { iD[r] = (lane >> 4) + 4 * r; jD[r] = lane & 15; }
            else if (dF == 2) { jD[r] = 4 * (lane >> 4) + r; iD[r] = lane & 15; }
            else              { jD[r] = (lane >> 4) + 4 * r; iD[r] = lane & 15; }
        }

        float* A0 = (float*)(smem + (size_t)w * 20480);
        float* B0 = A0 + 1280;
        float* A1 = A0 + 2560;
        float* B1 = A0 + 3840;

        d4 acc[4][4];
#pragma unroll
        for (int f = 0; f < 4; ++f)
#pragma unroll
            for (int g = 0; g < 4; ++g) acc[f][g] = (d4)0.0;

        float4 sa[4], sb[4];
        MFMA_LOAD(kw)                 // tile 0
        MFMA_STAGE(A0, B0)            // -> buf0
        MFMA_LOAD(kw + 32)            // tile 1

        for (int k0 = kw; k0 < N_DIM; k0 += 64) {
            MFMA_STAGE(A1, B1)        // tile k0+32 -> buf1
            if (k0 + 64 < N_DIM) { MFMA_LOAD(k0 + 64) }
            MFMA_COMPUTE(A0, B0)      // tile k0
            if (k0 + 64 < N_DIM) {
                MFMA_STAGE(A0, B0)    // tile k0+64 -> buf0
                if (k0 + 96 < N_DIM) { MFMA_LOAD(k0 + 96) }
            }
            MFMA_COMPUTE(A1, B1)      // tile k0+32
        }

        __syncthreads();
        if (w == 1) {
#pragma unroll
            for (int f = 0; f < 4; ++f)
#pragma unroll
                for (int g = 0; g < 4; ++g)
#pragma unroll
                    for (int r = 0; r < 4; ++r)
                        cbuf[((f * 4 + g) * 4 + r) * 64 + lane] = acc[f][g][r];
        }
        __syncthreads();
        if (w == 0) {
#pragma unroll
            for (int f = 0; f < 4; ++f)
#pragma unroll
                for (int g = 0; g < 4; ++g)
#pragma unroll
                    for (int r = 0; r < 4; ++r)
                        acc[f][g][r] += cbuf[((f * 4 + g) * 4 + r) * 64 + lane];
            // store C
#pragma unroll
            for (int f = 0; f < 4; ++f)
#pragma unroll
                for (int r = 0; r < 4; ++r) {
                    int row = row0 + 16 * f + iD[r];
                    double* Crow = C + (size_t)row * N_DIM + col0 + jD[r];
#pragma unroll
                    for (int g = 0; g < 4; ++g)
                        Crow[16 * g] = acc[f][g][r];
                }
            // layout-agnostic BN partials: scatter acc -> cbuf[row][col],
            // then column-sum (same-wave DS ordering -> no barrier needed)
#pragma unroll
            for (int f = 0; f < 4; ++f)
#pragma unroll
                for (int r = 0; r < 4; ++r)
#pragma unroll
                    for (int g = 0; g < 4; ++g)
                        cbuf[(16 * f + iD[r]) * 64 + 16 * g + jD[r]] = acc[f][g][r];
            double s = 0.0, q = 0.0;
#pragma unroll
            for (int r = 0; r < 64; ++r) {
                double v = cbuf[r * 64 + lane];
                s += v;
                q = fma(v, v, q);
            }
            psum [band * N_DIM + col0 + lane] = s;
            psum2[band * N_DIM + col0 + lane] = q;
        }
    } else {
        // ================= f64 VALU (DP vector-pipe) path =================
        // f64 staged in LDS: cvt f32->f64 once at stage time; inner loop is
        // pure ds_read_b128 + v_fma_f64.
        const int tx = lane & 7;
        const int ty = lane >> 3;
        double* Asd = (double*)smem + (size_t)w * 2176;  // 16 x 68 doubles
        double* Bsd = Asd + 1088;

        double acc[8][8];
#pragma unroll
        for (int i = 0; i < 8; ++i)
#pragma unroll
            for (int j = 0; j < 8; ++j) acc[i][j] = 0.0;

        float4 sa[4], sb[4];
#pragma unroll
        for (int j = 0; j < 4; ++j) {
            sa[j] = *(const float4*)(Ag + kw + 4 * j);
            sb[j] = *(const float4*)(Bg + kw + 4 * j);
        }
        for (int k0 = kw; k0 < N_DIM; k0 += 2 * BK) {
#pragma unroll
            for (int j = 0; j < 4; ++j) {
                Asd[(4 * j + 0) * SDD + lane] = (double)sa[j].x;
                Asd[(4 * j + 1) * SDD + lane] = (double)sa[j].y;
                Asd[(4 * j + 2) * SDD + lane] = (double)sa[j].z;
                Asd[(4 * j + 3) * SDD + lane] = (double)sa[j].w;
                Bsd[(4 * j + 0) * SDD + lane] = (double)sb[j].x;
                Bsd[(4 * j + 1) * SDD + lane] = (double)sb[j].y;
                Bsd[(4 * j + 2) * SDD + lane] = (double)sb[j].z;
                Bsd[(4 * j + 3) * SDD + lane] = (double)sb[j].w;
            }
            if (k0 + 2 * BK < N_DIM) {
#pragma unroll
                for (int j = 0; j < 4; ++j) {
                    sa[j] = *(const float4*)(Ag + k0 + 2 * BK + 4 * j);
                    sb[j] = *(const float4*)(Bg + k0 + 2 * BK + 4 * j);
                }
            }
#pragma unroll
            for (int k = 0; k < BK; ++k) {
                d2 a01 = *(const d2*)&Asd[k * SDD + 4 * ty];
                d2 a23 = *(const d2*)&Asd[k * SDD + 4 * ty + 2];
                d2 a45 = *(const d2*)&Asd[k * SDD + 32 + 4 * ty];
                d2 a67 = *(const d2*)&Asd[k * SDD + 32 + 4 * ty + 2];
                d2 b01 = *(const d2*)&Bsd[k * SDD + 4 * tx];
                d2 b23 = *(const d2*)&Bsd[k * SDD + 4 * tx + 2];
                d2 b45 = *(const d2*)&Bsd[k * SDD + 32 + 4 * tx];
                d2 b67 = *(const d2*)&Bsd[k * SDD + 32 + 4 * tx + 2];
                double a[8], b[8];
                a[0] = a01.x; a[1] = a01.y; a[2] = a23.x; a[3] = a23.y;
                a[4] = a45.x; a[5] = a45.y; a[6] = a67.x; a[7] = a67.y;
                b[0] = b01.x; b[1] = b01.y; b[2] = b23.x; b[3] = b23.y;
                b[4] = b45.x; b[5] = b45.y; b[6] = b67.x; b[7] = b67.y;
#pragma unroll
                for (int i = 0; i < 8; ++i)
#pragma unroll
                    for (int j = 0; j < 8; ++j)
                        acc[i][j] = fma(a[i], b[j], acc[i][j]);
            }
        }

        __syncthreads();
        if (w == 1) {
#pragma unroll
            for (int e = 0; e < 64; ++e)
                cbuf[e * 64 + lane] = acc[e >> 3][e & 7];
        }
        __syncthreads();
        if (w == 0) {
#pragma unroll
            for (int i = 0; i < 8; ++i)
#pragma unroll
                for (int j = 0; j < 8; ++j)
                    acc[i][j] += cbuf[(i * 8 + j) * 64 + lane];
#pragma unroll
            for (int i = 0; i < 8; ++i) {
                int r = row0 + ((i < 4) ? (4 * ty + i) : (32 + 4 * ty + i - 4));
                double* Crow = C + (size_t)r * N_DIM + col0;
#pragma unroll
                for (int jg = 0; jg < 2; ++jg) {
                    int cbase = (jg == 0) ? (4 * tx) : (32 + 4 * tx);
                    d2 v0, v1;
                    v0.x = acc[i][4 * jg + 0]; v0.y = acc[i][4 * jg + 1];
                    v1.x = acc[i][4 * jg + 2]; v1.y = acc[i][4 * jg + 3];
                    *(d2*)(Crow + cbase)     = v0;
                    *(d2*)(Crow + cbase + 2) = v1;
                }
            }
            // BN partials via cbuf scatter + column reduction
#pragma unroll
            for (int i = 0; i < 8; ++i) {
                int rr = (i < 4) ? (4 * ty + i) : (32 + 4 * ty + i - 4);
#pragma unroll
                for (int j = 0; j < 8; ++j) {
                    int cc = (j < 4) ? (4 * tx + j) : (32 + 4 * tx + j - 4);
                    cbuf[rr * 64 + cc] = acc[i][j];
                }
            }
            double s = 0.0, q = 0.0;
#pragma unroll
            for (int r = 0; r < 64; ++r) {
                double v = cbuf[r * 64 + lane];
                s += v;
                q = fma(v, v, q);
            }
            psum [band * N_DIM + col0 + lane] = s;
            psum2[band * N_DIM + col0 + lane] = q;
        }
    }
}

// ---- BN final: reduce 32 rowband partials, build scale/shift --------------
__global__ __launch_bounds__(256)
void col_stats_final(const double* __restrict__ psum, const double* __restrict__ psum2,
                     const float* __restrict__ gamma, const float* __restrict__ beta,
                     double* __restrict__ scale, double* __restrict__ shift) {
    int m = blockIdx.x * 256 + threadIdx.x;
    double s = 0.0, s2 = 0.0;
    for (int c = 0; c < 32; ++c) { s += psum[c * N_DIM + m]; s2 += psum2[c * N_DIM + m]; }
    double mean = s * (1.0 / 2048.0);
    double var = s2 * (1.0 / 2048.0) - mean * mean;
    double istd = 1.0 / sqrt(var + 1e-5);
    double sc = istd * (double)gamma[m];
    scale[m] = sc;
    shift[m] = (double)beta[m] - mean * sc;
}

// ---- fused BN-apply + triple LIF + output ---------------------------------
__global__ __launch_bounds__(256)
void fused_lif_kernel(const float* __restrict__ x, const double* __restrict__ h,
                      const double* __restrict__ scale, const double* __restrict__ shift,
                      const double* __restrict__ ssum, const double* __restrict__ tsum,
                      float* __restrict__ out) {
    int idx = blockIdx.x * 256 + threadIdx.x;
    int n = idx & (N_DIM - 1);
    int b = idx >> 11;
    double sc = scale[n], sh = shift[n];
    double ts = tsum[idx];
    double v1 = 0.0, v2 = 0.0, v3 = 0.0;
    for (int t = 0; t < T_DIM; ++t) {
        size_t off = (size_t)(t * B_DIM + b) * N_DIM + n;
        double hv = fma(h[off], sc, sh);
        v1 = v1 * 0.5 + hv;
        bool s1 = (v1 >= 1.0); if (s1) v1 = 0.0;
        double in2 = s1 ? ssum[t * B_DIM + b] : 0.0;
        v2 = v2 * 0.5 + in2;
        bool s2 = (v2 >= 1.0); if (s2) v2 = 0.0;
        double in3 = s1 ? ts : 0.0;
        v3 = v3 * 0.5 + in3;
        bool s3 = (v3 >= 1.0); if (s3) v3 = 0.0;
        out[off] = x[off] + ((s2 && s3) ? 1.0f : 0.0f);
    }
}

extern "C" void kernel_launch(void* const* d_in, const int* in_sizes, int n_in,
                              void* d_out, int out_size, void* d_ws, size_t ws_size,
                              hipStream_t stream) {
    const float* x     = (const float*)d_in[0];   // [16,128,2048]
    const float* W     = (const float*)d_in[1];   // [2048,2048]
    const float* gamma = (const float*)d_in[2];   // [2048]
    const float* beta  = (const float*)d_in[3];   // [2048]
    float* out = (float*)d_out;

    char* ws = (char*)d_ws;
    double* h     = (double*)(ws + WS_H);
    double* tsum  = (double*)(ws + WS_TSUM);
    double* psum  = (double*)(ws + WS_PSUM);
    double* psum2 = (double*)(ws + WS_PSUM2);
    double* ssum  = (double*)(ws + WS_SSUM);
    double* scale = (double*)(ws + WS_SCALE);
    double* shift = (double*)(ws + WS_SHIFT);
    unsigned int* flag = (unsigned int*)(ws + WS_FLAG);

    mfma_probe_kernel<<<1, 64, 0, stream>>>(flag);
    spatial_sum_kernel<<<TB, 256, 0, stream>>>(x, ssum);
    temporal_sum_kernel<<<(B_DIM * N_DIM) / 256, 256, 0, stream>>>(x, tsum);
    gemm_hybrid<<<dim3(N_DIM / 64, TB / 64), 128, 0, stream>>>(x, W, h, psum, psum2, flag);
    col_stats_final<<<8, 256, 0, stream>>>(psum, psum2, gamma, beta, scale, shift);
    fused_lif_kernel<<<(B_DIM * N_DIM) / 256, 256, 0, stream>>>(x, h, scale, shift, ssum, tsum, out);
}

// Round 2
// 368.661 us; speedup vs baseline: 1.1428x; 1.1428x over previous
//
#include <hip/hip_runtime.h>
#include <math.h>

// Problem constants
#define T_DIM 16
#define B_DIM 128
#define N_DIM 2048
#define TB    (T_DIM * B_DIM)   // 2048 rows of the GEMM

// Workspace layout (bytes). h now f32 (16MB used of 32MB reserved).
#define WS_H      0
#define WS_TSUM   33554432
#define WS_PSUM   35651584      // [32][2048] f64 per-rowband col sums
#define WS_PSUM2  36175872      // [32][2048] f64 per-rowband col sq-sums
#define WS_SSUM   36700160
#define WS_SCALE  36716544
#define WS_SHIFT  36732928
#define WS_FLAG   36749312

typedef __attribute__((ext_vector_type(2))) double d2;
typedef __attribute__((ext_vector_type(4))) double d4;

// ---- MFMA f64 wiring probe -------------------------------------------------
__device__ __forceinline__ double probeA(int m, int k) {
    return (double)((m * 7 + k * 13) % 23 - 11);
}
__device__ __forceinline__ double probeB(int k, int n) {
    return (double)((k * 5 + n * 3) % 19 - 9);
}

// Hypothesis encoding fh = ab*4 + dF;  ab = aF + 2*bF.
//  A-form 0: m=l&15,k=l>>4   1: m=l>>2,k=l&3
//  B-form 0: n=l&15,k=l>>4   1: n=l>>2,k=l&3
//  D-form 0: i=4*(l>>4)+r,j=l&15   1: i=(l>>4)+4r,j=l&15
//         2: j=4*(l>>4)+r,i=l&15   3: j=(l>>4)+4r,i=l&15
__global__ void mfma_probe_kernel(unsigned int* flag) {
    int l = threadIdx.x;                 // one wave
    __shared__ double Cref[16][16];
    int i0 = l >> 2, j0 = (l & 3) << 2;
    for (int jj = 0; jj < 4; ++jj) {
        double s = 0.0;
        for (int k = 0; k < 4; ++k) s += probeA(i0, k) * probeB(k, j0 + jj);
        Cref[i0][j0 + jj] = s;
    }
    __syncthreads();
    unsigned int win = 0xFFFFFFFFu;
    for (int ab = 0; ab < 4; ++ab) {
        int aF = ab & 1, bF = (ab >> 1) & 1;
        int mA = aF ? (l >> 2) : (l & 15);
        int kA = aF ? (l & 3)  : (l >> 4);
        int nB = bF ? (l >> 2) : (l & 15);
        int kB = bF ? (l & 3)  : (l >> 4);
        d4 d = (d4)0.0;
        d = __builtin_amdgcn_mfma_f64_16x16x4f64(probeA(mA, kA), probeB(kB, nB), d, 0, 0, 0);
        for (int dF = 0; dF < 4; ++dF) {
            double err = 0.0;
            for (int r = 0; r < 4; ++r) {
                int ii, jj;
                if (dF == 0)      { ii = 4 * (l >> 4) + r; jj = l & 15; }
                else if (dF == 1) { ii = (l >> 4) + 4 * r; jj = l & 15; }
                else if (dF == 2) { jj = 4 * (l >> 4) + r; ii = l & 15; }
                else              { jj = (l >> 4) + 4 * r; ii = l & 15; }
                err = fmax(err, fabs(d[r] - Cref[ii][jj]));
            }
            for (int off = 1; off < 64; off <<= 1)
                err = fmax(err, __shfl_xor(err, off, 64));
            if (err < 1e-9 && win == 0xFFFFFFFFu)
                win = (unsigned)(ab * 4 + dF);
        }
    }
    if (l == 0) flag[0] = win;
}

// ---- fused spatial(row) + temporal(t) sums: one launch --------------------
// blocks [0,TB): row sums over n.  blocks [TB, TB+B*N/256): t-sums.
__global__ __launch_bounds__(256)
void sums_kernel(const float* __restrict__ x, double* __restrict__ ssum,
                 double* __restrict__ tsum) {
    int bid = blockIdx.x;
    int tid = threadIdx.x;
    if (bid < TB) {
        const float* xr = x + (size_t)bid * N_DIM;
        double s = 0.0;
        for (int i = tid; i < N_DIM; i += 256) s += (double)xr[i];
        for (int off = 32; off > 0; off >>= 1) s += __shfl_down(s, off, 64);
        __shared__ double wsum[4];
        int lane = tid & 63, wv = tid >> 6;
        if (lane == 0) wsum[wv] = s;
        __syncthreads();
        if (tid == 0) ssum[bid] = (wsum[0] + wsum[1]) + (wsum[2] + wsum[3]);
    } else {
        int idx = (bid - TB) * 256 + tid;
        double s = 0.0;
        for (int t = 0; t < T_DIM; ++t)
            s += (double)x[(size_t)t * (B_DIM * N_DIM) + idx];
        tsum[idx] = s;
    }
}

// ---- GEMM h[row,m] = sum_n x[row,n] * W[m,n] ------------------------------
// v12: all-MFMA (v10's proven 292us structure; dual-pipe reverted -- R1
// showed the f64 vector path runs at 59% of its ideal and the f64 FMA HW
// appears shared between matrix and vector pipes). C now stored f32:
// reference computes h in f32 (~1e-5 accumulated error) and our exact-f64
// pipeline matched its spikes with absmax=0, so threshold margins exceed
// 1e-5; f32 h storage error (~3e-7) is 100x inside that. BN stats stay f64.
#define BK 16
#define SDD 68    // f64 vector-fallback stride (doubles)
#define STRD 80   // mfma path stride (2-way aliasing = free)

#define MFMA_LOAD(koff)                                             \
    _Pragma("unroll")                                               \
    for (int j = 0; j < 4; ++j) {                                   \
        sa[j] = *(const float4*)(Ag + (koff) + 4 * j);              \
        sb[j] = *(const float4*)(Bg + (koff) + 4 * j);              \
    }

#define MFMA_STAGE(Ab, Bb)                                          \
    _Pragma("unroll")                                               \
    for (int j = 0; j < 4; ++j) {                                   \
        (Ab)[(4 * j + 0) * STRD + lane] = sa[j].x;                  \
        (Ab)[(4 * j + 1) * STRD + lane] = sa[j].y;                  \
        (Ab)[(4 * j + 2) * STRD + lane] = sa[j].z;                  \
        (Ab)[(4 * j + 3) * STRD + lane] = sa[j].w;                  \
        (Bb)[(4 * j + 0) * STRD + lane] = sb[j].x;                  \
        (Bb)[(4 * j + 1) * STRD + lane] = sb[j].y;                  \
        (Bb)[(4 * j + 2) * STRD + lane] = sb[j].z;                  \
        (Bb)[(4 * j + 3) * STRD + lane] = sb[j].w;                  \
    }

#define MFMA_COMPUTE(Ab, Bb)                                        \
    _Pragma("unroll")                                               \
    for (int jq = 0; jq < 4; ++jq) {                                \
        double av[4], bv[4];                                        \
        _Pragma("unroll")                                           \
        for (int f = 0; f < 4; ++f)                                 \
            av[f] = (double)(Ab)[(4 * jq + kA) * STRD + 16 * f + mA]; \
        _Pragma("unroll")                                           \
        for (int g = 0; g < 4; ++g)                                 \
            bv[g] = (double)(Bb)[(4 * jq + kB) * STRD + 16 * g + nB]; \
        _Pragma("unroll")                                           \
        for (int f = 0; f < 4; ++f)                                 \
            _Pragma("unroll")                                       \
            for (int g = 0; g < 4; ++g)                             \
                acc[f][g] = __builtin_amdgcn_mfma_f64_16x16x4f64(   \
                    av[f], bv[g], acc[f][g], 0, 0, 0);              \
    }

__global__ __launch_bounds__(128, 2)
void gemm_hybrid(const float* __restrict__ A, const float* __restrict__ Bw,
                 float* __restrict__ C, double* __restrict__ psum,
                 double* __restrict__ psum2, const unsigned int* __restrict__ flag) {
    __shared__ __align__(16) char smem[40960];   // 2 waves x 2 bufs x 10240B; cbuf 32KB
    const int t    = threadIdx.x;
    const int lane = t & 63;
    const int w    = t >> 6;
    const int row0 = blockIdx.y * 64;
    const int col0 = blockIdx.x * 64;
    const int band = blockIdx.y;
    const unsigned int fh = flag[0];

    const float* Ag = A  + (size_t)(row0 + lane) * N_DIM;
    const float* Bg = Bw + (size_t)(col0 + lane) * N_DIM;
    const int kw = w * BK;
    double* cbuf = (double*)smem;                // 4096 doubles = 32KB

    if (fh <= 15u) {
        // ================= MFMA path =================
        const int dF = fh & 3, ab = fh >> 2;
        const int aF = ab & 1, bF = (ab >> 1) & 1;
        const int mA = aF ? (lane >> 2) : (lane & 15);
        const int kA = aF ? (lane & 3)  : (lane >> 4);
        const int nB = bF ? (lane >> 2) : (lane & 15);
        const int kB = bF ? (lane & 3)  : (lane >> 4);
        int iD[4], jD[4];
#pragma unroll
        for (int r = 0; r < 4; ++r) {
            if (dF == 0)      { iD[r] = 4 * (lane >> 4) + r; jD[r] = lane & 15; }
            else if (dF == 1) { iD[r] = (lane >> 4) + 4 * r; jD[r] = lane & 15; }
            else if (dF == 2) { jD[r] = 4 * (lane >> 4) + r; iD[r] = lane & 15; }
            else              { jD[r] = (lane >> 4) + 4 * r; iD[r] = lane & 15; }
        }

        float* A0 = (float*)(smem + (size_t)w * 20480);
        float* B0 = A0 + 1280;
        float* A1 = A0 + 2560;
        float* B1 = A0 + 3840;

        d4 acc[4][4];
#pragma unroll
        for (int f = 0; f < 4; ++f)
#pragma unroll
            for (int g = 0; g < 4; ++g) acc[f][g] = (d4)0.0;

        float4 sa[4], sb[4];
        MFMA_LOAD(kw)                 // tile 0
        MFMA_STAGE(A0, B0)            // -> buf0
        MFMA_LOAD(kw + 32)            // tile 1

        for (int k0 = kw; k0 < N_DIM; k0 += 64) {
            MFMA_STAGE(A1, B1)        // tile k0+32 -> buf1
            if (k0 + 64 < N_DIM) { MFMA_LOAD(k0 + 64) }
            MFMA_COMPUTE(A0, B0)      // tile k0
            if (k0 + 64 < N_DIM) {
                MFMA_STAGE(A0, B0)    // tile k0+64 -> buf0
                if (k0 + 96 < N_DIM) { MFMA_LOAD(k0 + 96) }
            }
            MFMA_COMPUTE(A1, B1)      // tile k0+32
        }

        __syncthreads();
        if (w == 1) {
#pragma unroll
            for (int f = 0; f < 4; ++f)
#pragma unroll
                for (int g = 0; g < 4; ++g)
#pragma unroll
                    for (int r = 0; r < 4; ++r)
                        cbuf[((f * 4 + g) * 4 + r) * 64 + lane] = acc[f][g][r];
        }
        __syncthreads();
        if (w == 0) {
#pragma unroll
            for (int f = 0; f < 4; ++f)
#pragma unroll
                for (int g = 0; g < 4; ++g)
#pragma unroll
                    for (int r = 0; r < 4; ++r)
                        acc[f][g][r] += cbuf[((f * 4 + g) * 4 + r) * 64 + lane];
            // store C (f32)
#pragma unroll
            for (int f = 0; f < 4; ++f)
#pragma unroll
                for (int r = 0; r < 4; ++r) {
                    int row = row0 + 16 * f + iD[r];
                    float* Crow = C + (size_t)row * N_DIM + col0 + jD[r];
#pragma unroll
                    for (int g = 0; g < 4; ++g)
                        Crow[16 * g] = (float)acc[f][g][r];
                }
            // layout-agnostic BN partials: scatter acc -> cbuf[row][col],
            // then column-sum (same-wave DS ordering -> no barrier needed)
#pragma unroll
            for (int f = 0; f < 4; ++f)
#pragma unroll
                for (int r = 0; r < 4; ++r)
#pragma unroll
                    for (int g = 0; g < 4; ++g)
                        cbuf[(16 * f + iD[r]) * 64 + 16 * g + jD[r]] = acc[f][g][r];
            double s = 0.0, q = 0.0;
#pragma unroll
            for (int r = 0; r < 64; ++r) {
                double v = cbuf[r * 64 + lane];
                s += v;
                q = fma(v, v, q);
            }
            psum [band * N_DIM + col0 + lane] = s;
            psum2[band * N_DIM + col0 + lane] = q;
        }
    } else {
        // ================= f64 VALU fallback (probe-fail only) =================
        const int tx = lane & 7;
        const int ty = lane >> 3;
        double* Asd = (double*)smem + (size_t)w * 2176;  // 16 x 68 doubles
        double* Bsd = Asd + 1088;

        double acc[8][8];
#pragma unroll
        for (int i = 0; i < 8; ++i)
#pragma unroll
            for (int j = 0; j < 8; ++j) acc[i][j] = 0.0;

        float4 sa[4], sb[4];
#pragma unroll
        for (int j = 0; j < 4; ++j) {
            sa[j] = *(const float4*)(Ag + kw + 4 * j);
            sb[j] = *(const float4*)(Bg + kw + 4 * j);
        }
        for (int k0 = kw; k0 < N_DIM; k0 += 2 * BK) {
#pragma unroll
            for (int j = 0; j < 4; ++j) {
                Asd[(4 * j + 0) * SDD + lane] = (double)sa[j].x;
                Asd[(4 * j + 1) * SDD + lane] = (double)sa[j].y;
                Asd[(4 * j + 2) * SDD + lane] = (double)sa[j].z;
                Asd[(4 * j + 3) * SDD + lane] = (double)sa[j].w;
                Bsd[(4 * j + 0) * SDD + lane] = (double)sb[j].x;
                Bsd[(4 * j + 1) * SDD + lane] = (double)sb[j].y;
                Bsd[(4 * j + 2) * SDD + lane] = (double)sb[j].z;
                Bsd[(4 * j + 3) * SDD + lane] = (double)sb[j].w;
            }
            if (k0 + 2 * BK < N_DIM) {
#pragma unroll
                for (int j = 0; j < 4; ++j) {
                    sa[j] = *(const float4*)(Ag + k0 + 2 * BK + 4 * j);
                    sb[j] = *(const float4*)(Bg + k0 + 2 * BK + 4 * j);
                }
            }
#pragma unroll
            for (int k = 0; k < BK; ++k) {
                d2 a01 = *(const d2*)&Asd[k * SDD + 4 * ty];
                d2 a23 = *(const d2*)&Asd[k * SDD + 4 * ty + 2];
                d2 a45 = *(const d2*)&Asd[k * SDD + 32 + 4 * ty];
                d2 a67 = *(const d2*)&Asd[k * SDD + 32 + 4 * ty + 2];
                d2 b01 = *(const d2*)&Bsd[k * SDD + 4 * tx];
                d2 b23 = *(const d2*)&Bsd[k * SDD + 4 * tx + 2];
                d2 b45 = *(const d2*)&Bsd[k * SDD + 32 + 4 * tx];
                d2 b67 = *(const d2*)&Bsd[k * SDD + 32 + 4 * tx + 2];
                double a[8], b[8];
                a[0] = a01.x; a[1] = a01.y; a[2] = a23.x; a[3] = a23.y;
                a[4] = a45.x; a[5] = a45.y; a[6] = a67.x; a[7] = a67.y;
                b[0] = b01.x; b[1] = b01.y; b[2] = b23.x; b[3] = b23.y;
                b[4] = b45.x; b[5] = b45.y; b[6] = b67.x; b[7] = b67.y;
#pragma unroll
                for (int i = 0; i < 8; ++i)
#pragma unroll
                    for (int j = 0; j < 8; ++j)
                        acc[i][j] = fma(a[i], b[j], acc[i][j]);
            }
        }

        __syncthreads();
        if (w == 1) {
#pragma unroll
            for (int e = 0; e < 64; ++e)
                cbuf[e * 64 + lane] = acc[e >> 3][e & 7];
        }
        __syncthreads();
        if (w == 0) {
#pragma unroll
            for (int i = 0; i < 8; ++i)
#pragma unroll
                for (int j = 0; j < 8; ++j)
                    acc[i][j] += cbuf[(i * 8 + j) * 64 + lane];
#pragma unroll
            for (int i = 0; i < 8; ++i) {
                int r = row0 + ((i < 4) ? (4 * ty + i) : (32 + 4 * ty + i - 4));
                float* Crow = C + (size_t)r * N_DIM + col0;
#pragma unroll
                for (int jg = 0; jg < 2; ++jg) {
                    int cbase = (jg == 0) ? (4 * tx) : (32 + 4 * tx);
                    float4 v;
                    v.x = (float)acc[i][4 * jg + 0]; v.y = (float)acc[i][4 * jg + 1];
                    v.z = (float)acc[i][4 * jg + 2]; v.w = (float)acc[i][4 * jg + 3];
                    *(float4*)(Crow + cbase) = v;
                }
            }
            // BN partials via cbuf scatter + column reduction
#pragma unroll
            for (int i = 0; i < 8; ++i) {
                int rr = (i < 4) ? (4 * ty + i) : (32 + 4 * ty + i - 4);
#pragma unroll
                for (int j = 0; j < 8; ++j) {
                    int cc = (j < 4) ? (4 * tx + j) : (32 + 4 * tx + j - 4);
                    cbuf[rr * 64 + cc] = acc[i][j];
                }
            }
            double s = 0.0, q = 0.0;
#pragma unroll
            for (int r = 0; r < 64; ++r) {
                double v = cbuf[r * 64 + lane];
                s += v;
                q = fma(v, v, q);
            }
            psum [band * N_DIM + col0 + lane] = s;
            psum2[band * N_DIM + col0 + lane] = q;
        }
    }
}

// ---- BN final: reduce 32 rowband partials, build scale/shift --------------
__global__ __launch_bounds__(256)
void col_stats_final(const double* __restrict__ psum, const double* __restrict__ psum2,
                     const float* __restrict__ gamma, const float* __restrict__ beta,
                     double* __restrict__ scale, double* __restrict__ shift) {
    int m = blockIdx.x * 256 + threadIdx.x;
    double s = 0.0, s2 = 0.0;
    for (int c = 0; c < 32; ++c) { s += psum[c * N_DIM + m]; s2 += psum2[c * N_DIM + m]; }
    double mean = s * (1.0 / 2048.0);
    double var = s2 * (1.0 / 2048.0) - mean * mean;
    double istd = 1.0 / sqrt(var + 1e-5);
    double sc = istd * (double)gamma[m];
    scale[m] = sc;
    shift[m] = (double)beta[m] - mean * sc;
}

// ---- fused BN-apply + triple LIF + output ---------------------------------
__global__ __launch_bounds__(256)
void fused_lif_kernel(const float* __restrict__ x, const float* __restrict__ h,
                      const double* __restrict__ scale, const double* __restrict__ shift,
                      const double* __restrict__ ssum, const double* __restrict__ tsum,
                      float* __restrict__ out) {
    int idx = blockIdx.x * 256 + threadIdx.x;
    int n = idx & (N_DIM - 1);
    int b = idx >> 11;
    double sc = scale[n], sh = shift[n];
    double ts = tsum[idx];
    double v1 = 0.0, v2 = 0.0, v3 = 0.0;
    for (int t = 0; t < T_DIM; ++t) {
        size_t off = (size_t)(t * B_DIM + b) * N_DIM + n;
        double hv = fma((double)h[off], sc, sh);
        v1 = v1 * 0.5 + hv;
        bool s1 = (v1 >= 1.0); if (s1) v1 = 0.0;
        double in2 = s1 ? ssum[t * B_DIM + b] : 0.0;
        v2 = v2 * 0.5 + in2;
        bool s2 = (v2 >= 1.0); if (s2) v2 = 0.0;
        double in3 = s1 ? ts : 0.0;
        v3 = v3 * 0.5 + in3;
        bool s3 = (v3 >= 1.0); if (s3) v3 = 0.0;
        out[off] = x[off] + ((s2 && s3) ? 1.0f : 0.0f);
    }
}

extern "C" void kernel_launch(void* const* d_in, const int* in_sizes, int n_in,
                              void* d_out, int out_size, void* d_ws, size_t ws_size,
                              hipStream_t stream) {
    const float* x     = (const float*)d_in[0];   // [16,128,2048]
    const float* W     = (const float*)d_in[1];   // [2048,2048]
    const float* gamma = (const float*)d_in[2];   // [2048]
    const float* beta  = (const float*)d_in[3];   // [2048]
    float* out = (float*)d_out;

    char* ws = (char*)d_ws;
    float*  h     = (float*)(ws + WS_H);
    double* tsum  = (double*)(ws + WS_TSUM);
    double* psum  = (double*)(ws + WS_PSUM);
    double* psum2 = (double*)(ws + WS_PSUM2);
    double* ssum  = (double*)(ws + WS_SSUM);
    double* scale = (double*)(ws + WS_SCALE);
    double* shift = (double*)(ws + WS_SHIFT);
    unsigned int* flag = (unsigned int*)(ws + WS_FLAG);

    mfma_probe_kernel<<<1, 64, 0, stream>>>(flag);
    sums_kernel<<<TB + (B_DIM * N_DIM) / 256, 256, 0, stream>>>(x, ssum, tsum);
    gemm_hybrid<<<dim3(N_DIM / 64, TB / 64), 128, 0, stream>>>(x, W, h, psum, psum2, flag);
    col_stats_final<<<8, 256, 0, stream>>>(psum, psum2, gamma, beta, scale, shift);
    fused_lif_kernel<<<(B_DIM * N_DIM) / 256, 256, 0, stream>>>(x, h, scale, shift, ssum, tsum, out);
}